// Round 1
// baseline (2137.122 us; speedup 1.0000x reference)
//
#include <hip/hip_runtime.h>

#define INF_F 3.402823466e+38f

__device__ __forceinline__ float f_add(float a, float b){ return __fadd_rn(a,b); }
__device__ __forceinline__ float f_sub(float a, float b){ return __fsub_rn(a,b); }
__device__ __forceinline__ float f_mul(float a, float b){ return __fmul_rn(a,b); }

// ---------------------------------------------------------------------------
// Kernel 1: farthest point sampling. One 256-thread block per batch (B=8).
// Exact numpy-matching FP ops (no FMA contraction) so argmax indices match.
// Writes new_xyz = xyz[fps_idx] directly into d_out.
// ---------------------------------------------------------------------------
__global__ __launch_bounds__(256) void fps_kernel(
    const float* __restrict__ xyz, const int* __restrict__ farthest_init,
    float* __restrict__ out_new_xyz)
{
    const int b   = blockIdx.x;
    const int tid = threadIdx.x;
    const int lane = tid & 63;
    const int wid  = tid >> 6;

    __shared__ float sx[4096], sy[4096], sz[4096];
    __shared__ int   hist[1024];
    __shared__ float rv[2][4];
    __shared__ int   ri[2][4];

    const float* xb = xyz + (size_t)b * 4096 * 3;
    for (int n = tid; n < 4096; n += 256) {
        sx[n] = xb[n*3+0]; sy[n] = xb[n*3+1]; sz[n] = xb[n*3+2];
    }
    __syncthreads();

    float dist[16];
    #pragma unroll
    for (int j = 0; j < 16; ++j) dist[j] = 1e10f;

    int far = farthest_init[b];
    int p = 0;
    for (int it = 0; it < 1024; ++it) {
        if (tid == 0) hist[it] = far;
        float cx = sx[far], cy = sy[far], cz = sz[far];
        float bv = -1.0f; int bi = 0;
        #pragma unroll
        for (int j = 0; j < 16; ++j) {
            int n = j * 256 + tid;
            float dx = f_sub(sx[n], cx);
            float dy = f_sub(sy[n], cy);
            float dz = f_sub(sz[n], cz);
            // exact reference order: (dx^2 + dy^2) + dz^2, no FMA
            float d = f_add(f_add(f_mul(dx,dx), f_mul(dy,dy)), f_mul(dz,dz));
            float nd = fminf(dist[j], d);
            dist[j] = nd;
            if (nd > bv) { bv = nd; bi = n; }   // strict > : first-max (lowest idx) wins
        }
        // wave butterfly argmax (ties -> lowest index)
        #pragma unroll
        for (int m = 1; m < 64; m <<= 1) {
            float ov = __shfl_xor(bv, m);
            int   oi = __shfl_xor(bi, m);
            if (ov > bv || (ov == bv && oi < bi)) { bv = ov; bi = oi; }
        }
        if (lane == 0) { rv[p][wid] = bv; ri[p][wid] = bi; }
        __syncthreads();
        float gv = rv[p][0]; int gi = ri[p][0];
        #pragma unroll
        for (int w = 1; w < 4; ++w) {
            float ov = rv[p][w]; int oi = ri[p][w];
            if (ov > gv || (ov == gv && oi < gi)) { gv = ov; gi = oi; }
        }
        far = gi;
        p ^= 1;   // double-buffered reduce slots: 1 barrier per iteration
    }
    __syncthreads();
    #pragma unroll
    for (int q = 0; q < 4; ++q) {
        int s  = q * 256 + tid;
        int id = hist[s];
        float* o = out_new_xyz + ((size_t)b * 1024 + s) * 3;
        o[0] = sx[id]; o[1] = sy[id]; o[2] = sz[id];
    }
}

// ---------------------------------------------------------------------------
// Kernel 2: fused kNN (top-32 of 4096) + 3-layer MLP + max-pool over K.
// One 256-thread block handles 8 centroids of one batch.
// Phase 1: wave per centroid (x2), exact reference distance form, stable
//          lexicographic (dist, idx) selection == lax.top_k(-dist, 32).
// Phase 2: thread = (s_local, k); weights via uniform scalar loads; maxpool
//          over the 32 k-lanes via shfl_xor.
// ---------------------------------------------------------------------------
__global__ __launch_bounds__(256) void knn_mlp_kernel(
    const float* __restrict__ xyz, const float* __restrict__ points,
    const float* __restrict__ w0, const float* __restrict__ b0,
    const float* __restrict__ w1, const float* __restrict__ b1,
    const float* __restrict__ w2, const float* __restrict__ b2,
    const float* __restrict__ new_xyz, float* __restrict__ out_np)
{
    const int blk    = blockIdx.x;
    const int b      = blk >> 7;           // 128 blocks per batch
    const int s_base = (blk & 127) * 8;
    const int tid    = threadIdx.x;
    const int lane   = tid & 63;
    const int wid    = tid >> 6;

    __shared__ float sx[4096], sy[4096], sz[4096];
    __shared__ float cent[8][3];
    __shared__ int   idxbuf[8][32];

    const float* xb = xyz + (size_t)b * 4096 * 3;
    for (int n = tid; n < 4096; n += 256) {
        sx[n] = xb[n*3+0]; sy[n] = xb[n*3+1]; sz[n] = xb[n*3+2];
    }
    if (tid < 24) ((float*)cent)[tid] = new_xyz[((size_t)b * 1024 + s_base) * 3 + tid];
    __syncthreads();

    // ---------------- phase 1: kNN ----------------
    for (int si = 0; si < 2; ++si) {
        const int sl = wid * 2 + si;
        const float cx = cent[sl][0], cy = cent[sl][1], cz = cent[sl][2];
        const float src2 = f_add(f_add(f_mul(cx,cx), f_mul(cy,cy)), f_mul(cz,cz));
        float d[64];
        #pragma unroll
        for (int j = 0; j < 64; ++j) {
            int n = j * 64 + lane;
            float x = sx[n], y = sy[n], z = sz[n];
            float dst2 = f_add(f_add(f_mul(x,x), f_mul(y,y)), f_mul(z,z));
            float dot  = f_add(f_add(f_mul(cx,x), f_mul(cy,y)), f_mul(cz,z));
            // exact reference: (src2 + dst2) - 2*dot
            d[j] = f_sub(f_add(src2, dst2), f_mul(2.0f, dot));
        }
        int myg  = 0;
        int prev = -1;
        for (int t = 0; t < 32; ++t) {
            float bv = INF_F; int bi = 0x7fffffff;
            #pragma unroll
            for (int j = 0; j < 64; ++j) {
                int n = j * 64 + lane;
                if (n == prev) d[j] = INF_F;    // invalidate last round's winner
                float v = d[j];
                if (v < bv) { bv = v; bi = n; } // strict < : lowest idx on ties
            }
            #pragma unroll
            for (int m = 1; m < 64; m <<= 1) {
                float ov = __shfl_xor(bv, m);
                int   oi = __shfl_xor(bi, m);
                if (ov < bv || (ov == bv && oi < bi)) { bv = ov; bi = oi; }
            }
            if (lane == t) myg = bi;
            prev = bi;
        }
        if (lane < 32) idxbuf[sl][lane] = myg;
    }
    __syncthreads();

    // ---------------- phase 2: MLP + maxpool ----------------
    const int k   = tid & 31;
    const int sl2 = tid >> 5;              // 0..7
    const int s   = s_base + sl2;
    const int n   = idxbuf[sl2][k];

    const float cx = cent[sl2][0], cy = cent[sl2][1], cz = cent[sl2][2];
    float h0[9];
    h0[0] = sx[n] - cx;
    h0[1] = sy[n] - cy;
    h0[2] = sz[n] - cz;
    const float* pp = points + ((size_t)b * 4096 + n) * 6;
    #pragma unroll
    for (int c = 0; c < 6; ++c) h0[3 + c] = pp[c];

    float h1[64];
    #pragma unroll
    for (int o = 0; o < 64; ++o) {
        float acc = b0[o];
        #pragma unroll
        for (int c = 0; c < 9; ++c) acc = fmaf(h0[c], w0[o*9+c], acc);
        h1[o] = fmaxf(acc, 0.0f);
    }

    float h2[64];
    #pragma unroll   // full unroll: keeps h2[] in registers (static indices)
    for (int o = 0; o < 64; ++o) {
        float acc = b1[o];
        #pragma unroll
        for (int c = 0; c < 64; ++c) acc = fmaf(h1[c], w1[o*64+c], acc);
        h2[o] = fmaxf(acc, 0.0f);
    }

    float* outp = out_np + ((size_t)b * 1024 + s) * 128;
    for (int og = 0; og < 4; ++og) {
        float keep = 0.0f;
        for (int o2 = 0; o2 < 32; ++o2) {
            const int o = og * 32 + o2;
            float acc = b2[o];
            #pragma unroll
            for (int c = 0; c < 64; ++c) acc = fmaf(h2[c], w2[o*64+c], acc);
            float m = fmaxf(acc, 0.0f);
            #pragma unroll
            for (int mm = 1; mm < 32; mm <<= 1)
                m = fmaxf(m, __shfl_xor(m, mm));   // max over the 32 k-lanes
            keep = (k == o2) ? m : keep;
        }
        outp[og * 32 + k] = keep;
    }
}

extern "C" void kernel_launch(void* const* d_in, const int* in_sizes, int n_in,
                              void* d_out, int out_size, void* d_ws, size_t ws_size,
                              hipStream_t stream) {
    const float* xyz           = (const float*)d_in[0];
    const float* points        = (const float*)d_in[1];
    const int*   farthest_init = (const int*)  d_in[2];
    const float* w0 = (const float*)d_in[3];
    const float* b0 = (const float*)d_in[4];
    const float* w1 = (const float*)d_in[5];
    const float* b1 = (const float*)d_in[6];
    const float* w2 = (const float*)d_in[7];
    const float* b2 = (const float*)d_in[8];

    float* out        = (float*)d_out;
    float* new_xyz    = out;                 // [8,1024,3]
    float* new_points = out + 8 * 1024 * 3;  // [8,1024,128]

    fps_kernel<<<8, 256, 0, stream>>>(xyz, farthest_init, new_xyz);
    knn_mlp_kernel<<<1024, 256, 0, stream>>>(xyz, points, w0, b0, w1, b1, w2, b2,
                                             new_xyz, new_points);
}

// Round 2
// 1866.910 us; speedup vs baseline: 1.1447x; 1.1447x over previous
//
#include <hip/hip_runtime.h>

#define INF_F 3.402823466e+38f

__device__ __forceinline__ float f_add(float a, float b){ return __fadd_rn(a,b); }
__device__ __forceinline__ float f_sub(float a, float b){ return __fsub_rn(a,b); }
__device__ __forceinline__ float f_mul(float a, float b){ return __fmul_rn(a,b); }

// ---------------------------------------------------------------------------
// Kernel 1: farthest point sampling. One 256-thread block per batch (B=8).
// Coordinates live in REGISTERS (16 pts/thread); LDS only for the centroid
// broadcast, cross-wave reduce, and final gather. Exact numpy-matching FP ops
// (no FMA contraction) so argmax indices match bit-for-bit.
// ---------------------------------------------------------------------------
__global__ __launch_bounds__(256) void fps_kernel(
    const float* __restrict__ xyz, const int* __restrict__ farthest_init,
    float* __restrict__ out_new_xyz)
{
    const int b   = blockIdx.x;
    const int tid = threadIdx.x;
    const int lane = tid & 63;
    const int wid  = tid >> 6;

    __shared__ float sx[4096], sy[4096], sz[4096];
    __shared__ int   hist[1024];
    __shared__ float rv[2][4];
    __shared__ int   ri[2][4];

    const float* xb = xyz + (size_t)b * 4096 * 3;
    for (int n = tid; n < 4096; n += 256) {
        sx[n] = xb[n*3+0]; sy[n] = xb[n*3+1]; sz[n] = xb[n*3+2];
    }
    __syncthreads();

    // register-resident coordinates: n = j*256 + tid
    float px[16], py[16], pz[16], dist[16];
    #pragma unroll
    for (int j = 0; j < 16; ++j) {
        const int n = j * 256 + tid;
        px[j] = sx[n]; py[j] = sy[n]; pz[j] = sz[n];
        dist[j] = 1e10f;
    }

    int far = farthest_init[b];
    int p = 0;
    for (int it = 0; it < 1024; ++it) {
        if (tid == 0) hist[it] = far;
        const float cx = sx[far], cy = sy[far], cz = sz[far];
        float bv = -1.0f; int bi = 0;
        #pragma unroll
        for (int j = 0; j < 16; ++j) {
            float dx = f_sub(px[j], cx);
            float dy = f_sub(py[j], cy);
            float dz = f_sub(pz[j], cz);
            // exact reference order: (dx^2 + dy^2) + dz^2, no FMA
            float d  = f_add(f_add(f_mul(dx,dx), f_mul(dy,dy)), f_mul(dz,dz));
            float nd = fminf(dist[j], d);
            dist[j] = nd;
            if (nd > bv) { bv = nd; bi = j * 256 + tid; } // strict >: lowest idx wins
        }
        // wave butterfly argmax (ties -> lowest index)
        #pragma unroll
        for (int m = 1; m < 64; m <<= 1) {
            float ov = __shfl_xor(bv, m);
            int   oi = __shfl_xor(bi, m);
            if (ov > bv || (ov == bv && oi < bi)) { bv = ov; bi = oi; }
        }
        if (lane == 0) { rv[p][wid] = bv; ri[p][wid] = bi; }
        __syncthreads();
        float gv = rv[p][0]; int gi = ri[p][0];
        #pragma unroll
        for (int w = 1; w < 4; ++w) {
            float ov = rv[p][w]; int oi = ri[p][w];
            if (ov > gv || (ov == gv && oi < gi)) { gv = ov; gi = oi; }
        }
        far = gi;
        p ^= 1;   // double-buffered reduce slots: 1 barrier per iteration
    }
    __syncthreads();
    #pragma unroll
    for (int q = 0; q < 4; ++q) {
        int s  = q * 256 + tid;
        int id = hist[s];
        float* o = out_new_xyz + ((size_t)b * 1024 + s) * 3;
        o[0] = sx[id]; o[1] = sy[id]; o[2] = sz[id];
    }
}

// ---------------------------------------------------------------------------
// Kernel 2: fused kNN (top-32 of 4096) + 3-layer MLP + max-pool over K.
// (unchanged this round — awaiting its counters once fps shrinks)
// ---------------------------------------------------------------------------
__global__ __launch_bounds__(256) void knn_mlp_kernel(
    const float* __restrict__ xyz, const float* __restrict__ points,
    const float* __restrict__ w0, const float* __restrict__ b0,
    const float* __restrict__ w1, const float* __restrict__ b1,
    const float* __restrict__ w2, const float* __restrict__ b2,
    const float* __restrict__ new_xyz, float* __restrict__ out_np)
{
    const int blk    = blockIdx.x;
    const int b      = blk >> 7;           // 128 blocks per batch
    const int s_base = (blk & 127) * 8;
    const int tid    = threadIdx.x;
    const int lane   = tid & 63;
    const int wid    = tid >> 6;

    __shared__ float sx[4096], sy[4096], sz[4096];
    __shared__ float cent[8][3];
    __shared__ int   idxbuf[8][32];

    const float* xb = xyz + (size_t)b * 4096 * 3;
    for (int n = tid; n < 4096; n += 256) {
        sx[n] = xb[n*3+0]; sy[n] = xb[n*3+1]; sz[n] = xb[n*3+2];
    }
    if (tid < 24) ((float*)cent)[tid] = new_xyz[((size_t)b * 1024 + s_base) * 3 + tid];
    __syncthreads();

    // ---------------- phase 1: kNN ----------------
    for (int si = 0; si < 2; ++si) {
        const int sl = wid * 2 + si;
        const float cx = cent[sl][0], cy = cent[sl][1], cz = cent[sl][2];
        const float src2 = f_add(f_add(f_mul(cx,cx), f_mul(cy,cy)), f_mul(cz,cz));
        float d[64];
        #pragma unroll
        for (int j = 0; j < 64; ++j) {
            int n = j * 64 + lane;
            float x = sx[n], y = sy[n], z = sz[n];
            float dst2 = f_add(f_add(f_mul(x,x), f_mul(y,y)), f_mul(z,z));
            float dot  = f_add(f_add(f_mul(cx,x), f_mul(cy,y)), f_mul(cz,z));
            // exact reference: (src2 + dst2) - 2*dot
            d[j] = f_sub(f_add(src2, dst2), f_mul(2.0f, dot));
        }
        int myg  = 0;
        int prev = -1;
        for (int t = 0; t < 32; ++t) {
            float bv = INF_F; int bi = 0x7fffffff;
            #pragma unroll
            for (int j = 0; j < 64; ++j) {
                int n = j * 64 + lane;
                if (n == prev) d[j] = INF_F;    // invalidate last round's winner
                float v = d[j];
                if (v < bv) { bv = v; bi = n; } // strict < : lowest idx on ties
            }
            #pragma unroll
            for (int m = 1; m < 64; m <<= 1) {
                float ov = __shfl_xor(bv, m);
                int   oi = __shfl_xor(bi, m);
                if (ov < bv || (ov == bv && oi < bi)) { bv = ov; bi = oi; }
            }
            if (lane == t) myg = bi;
            prev = bi;
        }
        if (lane < 32) idxbuf[sl][lane] = myg;
    }
    __syncthreads();

    // ---------------- phase 2: MLP + maxpool ----------------
    const int k   = tid & 31;
    const int sl2 = tid >> 5;              // 0..7
    const int s   = s_base + sl2;
    const int n   = idxbuf[sl2][k];

    const float cx = cent[sl2][0], cy = cent[sl2][1], cz = cent[sl2][2];
    float h0[9];
    h0[0] = sx[n] - cx;
    h0[1] = sy[n] - cy;
    h0[2] = sz[n] - cz;
    const float* pp = points + ((size_t)b * 4096 + n) * 6;
    #pragma unroll
    for (int c = 0; c < 6; ++c) h0[3 + c] = pp[c];

    float h1[64];
    #pragma unroll
    for (int o = 0; o < 64; ++o) {
        float acc = b0[o];
        #pragma unroll
        for (int c = 0; c < 9; ++c) acc = fmaf(h0[c], w0[o*9+c], acc);
        h1[o] = fmaxf(acc, 0.0f);
    }

    float h2[64];
    #pragma unroll   // full unroll: keeps h2[] in registers (static indices)
    for (int o = 0; o < 64; ++o) {
        float acc = b1[o];
        #pragma unroll
        for (int c = 0; c < 64; ++c) acc = fmaf(h1[c], w1[o*64+c], acc);
        h2[o] = fmaxf(acc, 0.0f);
    }

    float* outp = out_np + ((size_t)b * 1024 + s) * 128;
    for (int og = 0; og < 4; ++og) {
        float keep = 0.0f;
        for (int o2 = 0; o2 < 32; ++o2) {
            const int o = og * 32 + o2;
            float acc = b2[o];
            #pragma unroll
            for (int c = 0; c < 64; ++c) acc = fmaf(h2[c], w2[o*64+c], acc);
            float m = fmaxf(acc, 0.0f);
            #pragma unroll
            for (int mm = 1; mm < 32; mm <<= 1)
                m = fmaxf(m, __shfl_xor(m, mm));   // max over the 32 k-lanes
            keep = (k == o2) ? m : keep;
        }
        outp[og * 32 + k] = keep;
    }
}

extern "C" void kernel_launch(void* const* d_in, const int* in_sizes, int n_in,
                              void* d_out, int out_size, void* d_ws, size_t ws_size,
                              hipStream_t stream) {
    const float* xyz           = (const float*)d_in[0];
    const float* points        = (const float*)d_in[1];
    const int*   farthest_init = (const int*)  d_in[2];
    const float* w0 = (const float*)d_in[3];
    const float* b0 = (const float*)d_in[4];
    const float* w1 = (const float*)d_in[5];
    const float* b1 = (const float*)d_in[6];
    const float* w2 = (const float*)d_in[7];
    const float* b2 = (const float*)d_in[8];

    float* out        = (float*)d_out;
    float* new_xyz    = out;                 // [8,1024,3]
    float* new_points = out + 8 * 1024 * 3;  // [8,1024,128]

    fps_kernel<<<8, 256, 0, stream>>>(xyz, farthest_init, new_xyz);
    knn_mlp_kernel<<<1024, 256, 0, stream>>>(xyz, points, w0, b0, w1, b1, w2, b2,
                                             new_xyz, new_points);
}

// Round 3
// 887.095 us; speedup vs baseline: 2.4091x; 2.1045x over previous
//
#include <hip/hip_runtime.h>

#define INF_F 3.402823466e+38f
typedef unsigned long long u64;

__device__ __forceinline__ float f_add(float a, float b){ return __fadd_rn(a,b); }
__device__ __forceinline__ float f_sub(float a, float b){ return __fsub_rn(a,b); }
__device__ __forceinline__ float f_mul(float a, float b){ return __fmul_rn(a,b); }

// DPP cross-lane fetch (pure VALU): returns neighbor's value per CTRL pattern.
// 0xB1 = quad_perm(1,0,3,2) -> xor1 ; 0x4E = quad_perm(2,3,0,1) -> xor2
// 0x141 = row_half_mirror -> pairs 8-groups ; 0x140 = row_mirror -> pairs 16-groups
template<int CTRL>
__device__ __forceinline__ double dpp_d(double x) {
    u64 u = (u64)__double_as_longlong(x);
    int lo = __builtin_amdgcn_update_dpp(0, (int)(unsigned)u,        CTRL, 0xF, 0xF, true);
    int hi = __builtin_amdgcn_update_dpp(0, (int)(unsigned)(u>>32), CTRL, 0xF, 0xF, true);
    return __longlong_as_double((long long)(((u64)(unsigned)hi << 32) | (unsigned)lo));
}

// xor-16 partner via ds_swizzle (BitMode 0x401F), both halves of the double.
__device__ __forceinline__ double swz16_d(double x) {
    u64 u = (u64)__double_as_longlong(x);
    int lo = __builtin_amdgcn_ds_swizzle((int)(unsigned)u,        0x401F);
    int hi = __builtin_amdgcn_ds_swizzle((int)(unsigned)(u>>32), 0x401F);
    return __longlong_as_double((long long)(((u64)(unsigned)hi << 32) | (unsigned)lo));
}

// ---------------------------------------------------------------------------
// Kernel 1: farthest point sampling. One 256-thread block per batch (B=8).
// Coordinates in registers; argmax via packed f64 key (bits(nd)<<32)|(4095-n)
// so max == (value, lowest-index) lexicographic, matching np.argmax exactly.
// Wave reduce: 4 DPP stages (VALU) -> 16 LDS slots -> fmax tree.
// ---------------------------------------------------------------------------
__global__ __launch_bounds__(256) void fps_kernel(
    const float* __restrict__ xyz, const int* __restrict__ farthest_init,
    float* __restrict__ out_new_xyz)
{
    const int b    = blockIdx.x;
    const int tid  = threadIdx.x;
    const int lane = tid & 63;
    const int wid  = tid >> 6;

    __shared__ float  sx[4096], sy[4096], sz[4096];
    __shared__ int    hist[1024];
    __shared__ double red[2][16];

    const float* xb = xyz + (size_t)b * 4096 * 3;
    for (int n = tid; n < 4096; n += 256) {
        sx[n] = xb[n*3+0]; sy[n] = xb[n*3+1]; sz[n] = xb[n*3+2];
    }
    __syncthreads();

    float px[16], py[16], pz[16], dist[16];
    #pragma unroll
    for (int j = 0; j < 16; ++j) {
        const int n = j * 256 + tid;
        px[j] = sx[n]; py[j] = sy[n]; pz[j] = sz[n];
        dist[j] = 1e10f;
    }
    const unsigned lowbase = 4095u - (unsigned)tid;

    int far = farthest_init[b];
    int p = 0;
    #pragma unroll 1
    for (int it = 0; it < 1024; ++it) {
        if (tid == 0) hist[it] = far;
        const float cx = sx[far], cy = sy[far], cz = sz[far];

        double kk[16];
        #pragma unroll
        for (int j = 0; j < 16; ++j) {
            float dx = f_sub(px[j], cx);
            float dy = f_sub(py[j], cy);
            float dz = f_sub(pz[j], cz);
            // exact reference order: (dx^2 + dy^2) + dz^2, no FMA
            float d  = f_add(f_add(f_mul(dx,dx), f_mul(dy,dy)), f_mul(dz,dz));
            float nd = fminf(dist[j], d);
            dist[j] = nd;
            kk[j] = __longlong_as_double((long long)(
                      ((u64)__float_as_uint(nd) << 32) | (u64)(lowbase - 256u*(unsigned)j)));
        }
        // per-lane tree max over 16 keys
        #pragma unroll
        for (int st = 8; st; st >>= 1)
            #pragma unroll
            for (int i = 0; i < st; ++i) kk[i] = fmax(kk[i], kk[i+st]);
        double key = kk[0];
        // in-wave: reduce to 16-lane groups (all VALU via DPP)
        key = fmax(key, dpp_d<0xB1>(key));
        key = fmax(key, dpp_d<0x4E>(key));
        key = fmax(key, dpp_d<0x141>(key));
        key = fmax(key, dpp_d<0x140>(key));
        if ((lane & 15) == 0) red[p][wid*4 + (lane>>4)] = key;
        __syncthreads();
        double r[16];
        #pragma unroll
        for (int i = 0; i < 16; ++i) r[i] = red[p][i];
        #pragma unroll
        for (int st = 8; st; st >>= 1)
            #pragma unroll
            for (int i = 0; i < st; ++i) r[i] = fmax(r[i], r[i+st]);
        far = 4095 - (int)(unsigned)((u64)__double_as_longlong(r[0]) & 0xFFFFFFFFull);
        p ^= 1;
    }
    __syncthreads();
    #pragma unroll
    for (int q = 0; q < 4; ++q) {
        int s  = q * 256 + tid;
        int id = hist[s];
        float* o = out_new_xyz + ((size_t)b * 1024 + s) * 3;
        o[0] = sx[id]; o[1] = sy[id]; o[2] = sz[id];
    }
}

// ---------------------------------------------------------------------------
// Kernel 2: kNN top-32 of 4096. One wave per centroid, 8192 blocks x 64.
// No LDS: xyz is L2-resident. Distances packed once into DISTINCT f64 keys
// (bits(d)<<32)|n -> min == (dist, lowest-idx) lexicographic == lax.top_k.
// Rounds: branch-free filtered min (keys > last winner), no invalidation.
// ---------------------------------------------------------------------------
__global__ __launch_bounds__(64) void knn_kernel(
    const float* __restrict__ xyz, const float* __restrict__ new_xyz,
    int* __restrict__ out_idx)
{
    const int blk  = blockIdx.x;           // 0..8191 = b*1024 + s
    const int b    = blk >> 10;
    const int lane = threadIdx.x;
    const double DINF = __builtin_huge_val();

    const float* xb = xyz + (size_t)b * 4096 * 3;
    const float* cp = new_xyz + (size_t)blk * 3;
    const float cx = cp[0], cy = cp[1], cz = cp[2];
    const float src2 = f_add(f_add(f_mul(cx,cx), f_mul(cy,cy)), f_mul(cz,cz));

    double key[64];
    #pragma unroll
    for (int j = 0; j < 64; ++j) {
        const int n = j * 64 + lane;
        const float* pt = xb + n * 3;
        float x = pt[0], y = pt[1], z = pt[2];
        float dst2 = f_add(f_add(f_mul(x,x), f_mul(y,y)), f_mul(z,z));
        float dot  = f_add(f_add(f_mul(cx,x), f_mul(cy,y)), f_mul(cz,z));
        // exact reference: (src2 + dst2) - 2*dot
        float d = f_sub(f_add(src2, dst2), f_mul(2.0f, dot));
        key[j] = __longlong_as_double((long long)(((u64)__float_as_uint(d) << 32) | (u64)(unsigned)n));
    }

    double w = -1.0;            // all keys are > -1.0 (tiny-negative d keys included)
    int myidx = 0;
    #pragma unroll 1
    for (int t = 0; t < 32; ++t) {
        double acc = DINF;
        #pragma unroll
        for (int j = 0; j < 64; ++j) {
            double v = (key[j] > w) ? key[j] : DINF;
            acc = fmin(acc, v);
        }
        acc = fmin(acc, dpp_d<0xB1>(acc));
        acc = fmin(acc, dpp_d<0x4E>(acc));
        acc = fmin(acc, dpp_d<0x141>(acc));
        acc = fmin(acc, dpp_d<0x140>(acc));
        acc = fmin(acc, swz16_d(acc));
        acc = fmin(acc, (double)__shfl_xor(acc, 32));
        if (lane == t) myidx = (int)(unsigned)((u64)__double_as_longlong(acc) & 0xFFFFFFFFull);
        w = acc;
    }
    if (lane < 32) out_idx[(size_t)blk * 32 + lane] = myidx;
}

// ---------------------------------------------------------------------------
// Kernel 3: 3-layer MLP + max-pool over K=32. thread = (centroid, k).
// Weights via uniform scalar loads; gathers from L2-resident xyz/points.
// ---------------------------------------------------------------------------
__global__ __launch_bounds__(256) void mlp_kernel(
    const float* __restrict__ xyz, const float* __restrict__ points,
    const int* __restrict__ knn_idx,
    const float* __restrict__ w0, const float* __restrict__ b0,
    const float* __restrict__ w1, const float* __restrict__ b1,
    const float* __restrict__ w2, const float* __restrict__ b2,
    const float* __restrict__ new_xyz, float* __restrict__ out_np)
{
    const int tid = threadIdx.x;
    const int k   = tid & 31;
    const int gs  = blockIdx.x * 8 + (tid >> 5);   // 0..8191
    const int b   = gs >> 10;
    const int n   = knn_idx[(size_t)gs * 32 + k];

    const float cx = new_xyz[gs*3+0], cy = new_xyz[gs*3+1], cz = new_xyz[gs*3+2];
    const float* pxyz = xyz + ((size_t)b * 4096 + n) * 3;
    float h0[9];
    h0[0] = pxyz[0] - cx;
    h0[1] = pxyz[1] - cy;
    h0[2] = pxyz[2] - cz;
    const float* pp = points + ((size_t)b * 4096 + n) * 6;
    #pragma unroll
    for (int c = 0; c < 6; ++c) h0[3 + c] = pp[c];

    float h1[64];
    #pragma unroll
    for (int o = 0; o < 64; ++o) {
        float acc = b0[o];
        #pragma unroll
        for (int c = 0; c < 9; ++c) acc = fmaf(h0[c], w0[o*9+c], acc);
        h1[o] = fmaxf(acc, 0.0f);
    }

    float h2[64];
    #pragma unroll
    for (int o = 0; o < 64; ++o) {
        float acc = b1[o];
        #pragma unroll
        for (int c = 0; c < 64; ++c) acc = fmaf(h1[c], w1[o*64+c], acc);
        h2[o] = fmaxf(acc, 0.0f);
    }

    float* outp = out_np + (size_t)gs * 128;
    for (int og = 0; og < 4; ++og) {
        float keep = 0.0f;
        for (int o2 = 0; o2 < 32; ++o2) {
            const int o = og * 32 + o2;
            float acc = b2[o];
            #pragma unroll
            for (int c = 0; c < 64; ++c) acc = fmaf(h2[c], w2[o*64+c], acc);
            float m = fmaxf(acc, 0.0f);
            #pragma unroll
            for (int mm = 1; mm < 32; mm <<= 1)
                m = fmaxf(m, __shfl_xor(m, mm));   // max over the 32 k-lanes
            keep = (k == o2) ? m : keep;
        }
        outp[og * 32 + k] = keep;
    }
}

// ---------------------------------------------------------------------------
// Fallback (ws too small): original fused kNN+MLP (known-correct).
// ---------------------------------------------------------------------------
__global__ __launch_bounds__(256) void knn_mlp_kernel(
    const float* __restrict__ xyz, const float* __restrict__ points,
    const float* __restrict__ w0, const float* __restrict__ b0,
    const float* __restrict__ w1, const float* __restrict__ b1,
    const float* __restrict__ w2, const float* __restrict__ b2,
    const float* __restrict__ new_xyz, float* __restrict__ out_np)
{
    const int blk    = blockIdx.x;
    const int b      = blk >> 7;
    const int s_base = (blk & 127) * 8;
    const int tid    = threadIdx.x;
    const int lane   = tid & 63;
    const int wid    = tid >> 6;

    __shared__ float sx[4096], sy[4096], sz[4096];
    __shared__ float cent[8][3];
    __shared__ int   idxbuf[8][32];

    const float* xb = xyz + (size_t)b * 4096 * 3;
    for (int n = tid; n < 4096; n += 256) {
        sx[n] = xb[n*3+0]; sy[n] = xb[n*3+1]; sz[n] = xb[n*3+2];
    }
    if (tid < 24) ((float*)cent)[tid] = new_xyz[((size_t)b * 1024 + s_base) * 3 + tid];
    __syncthreads();

    for (int si = 0; si < 2; ++si) {
        const int sl = wid * 2 + si;
        const float cx = cent[sl][0], cy = cent[sl][1], cz = cent[sl][2];
        const float src2 = f_add(f_add(f_mul(cx,cx), f_mul(cy,cy)), f_mul(cz,cz));
        float d[64];
        #pragma unroll
        for (int j = 0; j < 64; ++j) {
            int n = j * 64 + lane;
            float x = sx[n], y = sy[n], z = sz[n];
            float dst2 = f_add(f_add(f_mul(x,x), f_mul(y,y)), f_mul(z,z));
            float dot  = f_add(f_add(f_mul(cx,x), f_mul(cy,y)), f_mul(cz,z));
            d[j] = f_sub(f_add(src2, dst2), f_mul(2.0f, dot));
        }
        int myg  = 0;
        int prev = -1;
        for (int t = 0; t < 32; ++t) {
            float bv = INF_F; int bi = 0x7fffffff;
            #pragma unroll
            for (int j = 0; j < 64; ++j) {
                int n = j * 64 + lane;
                if (n == prev) d[j] = INF_F;
                float v = d[j];
                if (v < bv) { bv = v; bi = n; }
            }
            #pragma unroll
            for (int m = 1; m < 64; m <<= 1) {
                float ov = __shfl_xor(bv, m);
                int   oi = __shfl_xor(bi, m);
                if (ov < bv || (ov == bv && oi < bi)) { bv = ov; bi = oi; }
            }
            if (lane == t) myg = bi;
            prev = bi;
        }
        if (lane < 32) idxbuf[sl][lane] = myg;
    }
    __syncthreads();

    const int k   = tid & 31;
    const int sl2 = tid >> 5;
    const int s   = s_base + sl2;
    const int n   = idxbuf[sl2][k];

    const float cx = cent[sl2][0], cy = cent[sl2][1], cz = cent[sl2][2];
    float h0[9];
    h0[0] = sx[n] - cx;
    h0[1] = sy[n] - cy;
    h0[2] = sz[n] - cz;
    const float* pp = points + ((size_t)b * 4096 + n) * 6;
    #pragma unroll
    for (int c = 0; c < 6; ++c) h0[3 + c] = pp[c];

    float h1[64];
    #pragma unroll
    for (int o = 0; o < 64; ++o) {
        float acc = b0[o];
        #pragma unroll
        for (int c = 0; c < 9; ++c) acc = fmaf(h0[c], w0[o*9+c], acc);
        h1[o] = fmaxf(acc, 0.0f);
    }
    float h2[64];
    #pragma unroll
    for (int o = 0; o < 64; ++o) {
        float acc = b1[o];
        #pragma unroll
        for (int c = 0; c < 64; ++c) acc = fmaf(h1[c], w1[o*64+c], acc);
        h2[o] = fmaxf(acc, 0.0f);
    }
    float* outp = out_np + ((size_t)b * 1024 + s) * 128;
    for (int og = 0; og < 4; ++og) {
        float keep = 0.0f;
        for (int o2 = 0; o2 < 32; ++o2) {
            const int o = og * 32 + o2;
            float acc = b2[o];
            #pragma unroll
            for (int c = 0; c < 64; ++c) acc = fmaf(h2[c], w2[o*64+c], acc);
            float m = fmaxf(acc, 0.0f);
            #pragma unroll
            for (int mm = 1; mm < 32; mm <<= 1)
                m = fmaxf(m, __shfl_xor(m, mm));
            keep = (k == o2) ? m : keep;
        }
        outp[og * 32 + k] = keep;
    }
}

extern "C" void kernel_launch(void* const* d_in, const int* in_sizes, int n_in,
                              void* d_out, int out_size, void* d_ws, size_t ws_size,
                              hipStream_t stream) {
    const float* xyz           = (const float*)d_in[0];
    const float* points        = (const float*)d_in[1];
    const int*   farthest_init = (const int*)  d_in[2];
    const float* w0 = (const float*)d_in[3];
    const float* b0 = (const float*)d_in[4];
    const float* w1 = (const float*)d_in[5];
    const float* b1 = (const float*)d_in[6];
    const float* w2 = (const float*)d_in[7];
    const float* b2 = (const float*)d_in[8];

    float* out        = (float*)d_out;
    float* new_xyz    = out;                 // [8,1024,3]
    float* new_points = out + 8 * 1024 * 3;  // [8,1024,128]

    fps_kernel<<<8, 256, 0, stream>>>(xyz, farthest_init, new_xyz);

    if (ws_size >= (size_t)(8192 * 32 * sizeof(int))) {
        int* knn_idx = (int*)d_ws;
        knn_kernel<<<8192, 64, 0, stream>>>(xyz, new_xyz, knn_idx);
        mlp_kernel<<<1024, 256, 0, stream>>>(xyz, points, knn_idx,
                                             w0, b0, w1, b1, w2, b2,
                                             new_xyz, new_points);
    } else {
        knn_mlp_kernel<<<1024, 256, 0, stream>>>(xyz, points, w0, b0, w1, b1, w2, b2,
                                                 new_xyz, new_points);
    }
}

// Round 4
// 795.560 us; speedup vs baseline: 2.6863x; 1.1151x over previous
//
#include <hip/hip_runtime.h>

#define INF_F 3.402823466e+38f
typedef unsigned long long u64;
typedef __attribute__((ext_vector_type(2))) float f32x2;

__device__ __forceinline__ float f_add(float a, float b){ return __fadd_rn(a,b); }
__device__ __forceinline__ float f_sub(float a, float b){ return __fsub_rn(a,b); }
__device__ __forceinline__ float f_mul(float a, float b){ return __fmul_rn(a,b); }

// Packed fp32 (VOP3P) — same RN rounding as scalar, 2 elems/instr.
__device__ __forceinline__ f32x2 pk_add(f32x2 a, f32x2 b){ f32x2 d; asm("v_pk_add_f32 %0, %1, %2" : "=v"(d) : "v"(a), "v"(b)); return d; }
__device__ __forceinline__ f32x2 pk_mul(f32x2 a, f32x2 b){ f32x2 d; asm("v_pk_mul_f32 %0, %1, %2" : "=v"(d) : "v"(a), "v"(b)); return d; }

// DPP cross-lane (pure VALU). 0xB1=xor1, 0x4E=xor2, 0x141=xor4(eq), 0x140=xor8(eq)
template<int CTRL>
__device__ __forceinline__ double dpp_d(double x) {
    u64 u = (u64)__double_as_longlong(x);
    int lo = __builtin_amdgcn_update_dpp(0, (int)(unsigned)u,        CTRL, 0xF, 0xF, true);
    int hi = __builtin_amdgcn_update_dpp(0, (int)(unsigned)(u>>32), CTRL, 0xF, 0xF, true);
    return __longlong_as_double((long long)(((u64)(unsigned)hi << 32) | (unsigned)lo));
}
template<int CTRL>
__device__ __forceinline__ float dpp_f(float x) {
    int r = __builtin_amdgcn_update_dpp(0, __float_as_int(x), CTRL, 0xF, 0xF, true);
    return __int_as_float(r);
}
__device__ __forceinline__ double swz16_d(double x) {   // xor-16 partner
    u64 u = (u64)__double_as_longlong(x);
    int lo = __builtin_amdgcn_ds_swizzle((int)(unsigned)u,        0x401F);
    int hi = __builtin_amdgcn_ds_swizzle((int)(unsigned)(u>>32), 0x401F);
    return __longlong_as_double((long long)(((u64)(unsigned)hi << 32) | (unsigned)lo));
}
__device__ __forceinline__ float swz16_f(float x) {
    return __int_as_float(__builtin_amdgcn_ds_swizzle(__float_as_int(x), 0x401F));
}
__device__ __forceinline__ double readlane_d(double x, int l) {
    u64 u = (u64)__double_as_longlong(x);
    int lo = __builtin_amdgcn_readlane((int)(unsigned)u,        l);
    int hi = __builtin_amdgcn_readlane((int)(unsigned)(u>>32), l);
    return __longlong_as_double((long long)(((u64)(unsigned)hi << 32) | (unsigned)lo));
}

// ---------------------------------------------------------------------------
// Kernel 1: FPS. One 256-thread block per batch. Coordinates in registers as
// f32x2 pairs; distance update via packed fp32 (exact RN, reference op order).
// Argmax key = (bits(nd)<<32)|(4095-n) as f64 -> fmax == (val, lowest-idx).
// ---------------------------------------------------------------------------
__global__ __launch_bounds__(256) void fps_kernel(
    const float* __restrict__ xyz, const int* __restrict__ farthest_init,
    float* __restrict__ out_new_xyz)
{
    const int b    = blockIdx.x;
    const int tid  = threadIdx.x;
    const int lane = tid & 63;
    const int wid  = tid >> 6;

    __shared__ float  sx[4096], sy[4096], sz[4096];
    __shared__ int    hist[1024];
    __shared__ double red[2][16];

    const float* xb = xyz + (size_t)b * 4096 * 3;
    for (int n = tid; n < 4096; n += 256) {
        sx[n] = xb[n*3+0]; sy[n] = xb[n*3+1]; sz[n] = xb[n*3+2];
    }
    __syncthreads();

    f32x2 px[8], py[8], pz[8];
    float dist[16];
    unsigned lowv[16];
    #pragma unroll
    for (int jp = 0; jp < 8; ++jp) {
        const int n0 = (2*jp) * 256 + tid, n1 = n0 + 256;
        px[jp] = (f32x2){sx[n0], sx[n1]};
        py[jp] = (f32x2){sy[n0], sy[n1]};
        pz[jp] = (f32x2){sz[n0], sz[n1]};
    }
    #pragma unroll
    for (int j = 0; j < 16; ++j) { dist[j] = 1e10f; lowv[j] = 4095u - (unsigned)(j*256 + tid); }

    int far = farthest_init[b];
    int p = 0;
    #pragma unroll 1
    for (int it = 0; it < 1024; ++it) {
        if (tid == 0) hist[it] = far;
        const float cx = sx[far], cy = sy[far], cz = sz[far];
        const f32x2 ncx = (f32x2){-cx, -cx};
        const f32x2 ncy = (f32x2){-cy, -cy};
        const f32x2 ncz = (f32x2){-cz, -cz};

        double kk[16];
        #pragma unroll
        for (int jp = 0; jp < 8; ++jp) {
            f32x2 dx = pk_add(px[jp], ncx);          // x + (-c) == x - c exactly
            f32x2 dy = pk_add(py[jp], ncy);
            f32x2 dz = pk_add(pz[jp], ncz);
            // exact reference order: (dx^2 + dy^2) + dz^2, no FMA
            f32x2 d2 = pk_add(pk_add(pk_mul(dx,dx), pk_mul(dy,dy)), pk_mul(dz,dz));
            float nd0 = fminf(dist[2*jp+0], d2.x); dist[2*jp+0] = nd0;
            float nd1 = fminf(dist[2*jp+1], d2.y); dist[2*jp+1] = nd1;
            kk[2*jp+0] = __longlong_as_double((long long)(((u64)__float_as_uint(nd0) << 32) | (u64)lowv[2*jp+0]));
            kk[2*jp+1] = __longlong_as_double((long long)(((u64)__float_as_uint(nd1) << 32) | (u64)lowv[2*jp+1]));
        }
        #pragma unroll
        for (int st = 8; st; st >>= 1)
            #pragma unroll
            for (int i = 0; i < st; ++i) kk[i] = fmax(kk[i], kk[i+st]);
        double key = kk[0];
        key = fmax(key, dpp_d<0xB1>(key));
        key = fmax(key, dpp_d<0x4E>(key));
        key = fmax(key, dpp_d<0x141>(key));
        key = fmax(key, dpp_d<0x140>(key));
        if ((lane & 15) == 0) red[p][wid*4 + (lane>>4)] = key;
        __syncthreads();
        double r[16];
        #pragma unroll
        for (int i = 0; i < 16; ++i) r[i] = red[p][i];
        #pragma unroll
        for (int st = 8; st; st >>= 1)
            #pragma unroll
            for (int i = 0; i < st; ++i) r[i] = fmax(r[i], r[i+st]);
        far = 4095 - (int)(unsigned)((u64)__double_as_longlong(r[0]) & 0xFFFFFFFFull);
        p ^= 1;
    }
    __syncthreads();
    #pragma unroll
    for (int q = 0; q < 4; ++q) {
        int s  = q * 256 + tid;
        int id = hist[s];
        float* o = out_new_xyz + ((size_t)b * 1024 + s) * 3;
        o[0] = sx[id]; o[1] = sy[id]; o[2] = sz[id];
    }
}

// ---------------------------------------------------------------------------
// Kernel 2: kNN top-32. One wave per centroid (4 waves/block, no barriers).
// f64 keys (bits(d)<<32)|n, distinct -> min == (dist, lowest idx) == top_k.
// Per lane: 8 cached group-minima; per round rebuild only the winner's group
// (wave-uniform switch). w grows monotonically -> one filter excludes all
// previously extracted keys.
// ---------------------------------------------------------------------------
template<int G>
__device__ __forceinline__ double rebuild8(const double (&key)[64], double w) {
    const double DINF = __builtin_huge_val();
    double m = DINF;
    #pragma unroll
    for (int e = 0; e < 8; ++e) {
        double v = key[G*8+e];
        v = (v > w) ? v : DINF;
        m = fmin(m, v);
    }
    return m;
}

__global__ __launch_bounds__(256) void knn_kernel(
    const float* __restrict__ xyz, const float* __restrict__ new_xyz,
    int* __restrict__ out_idx)
{
    const int tid  = threadIdx.x;
    const int lane = tid & 63;
    const int wid  = tid >> 6;
    const int blk  = blockIdx.x * 4 + wid;   // 0..8191 = b*1024 + s
    const int b    = blk >> 10;
    const double DINF = __builtin_huge_val();

    const float* xb = xyz + (size_t)b * 4096 * 3;
    const float* cp = new_xyz + (size_t)blk * 3;
    const float cx = cp[0], cy = cp[1], cz = cp[2];
    const float src2 = f_add(f_add(f_mul(cx,cx), f_mul(cy,cy)), f_mul(cz,cz));

    double key[64];
    #pragma unroll
    for (int j = 0; j < 64; ++j) {
        const int n = j * 64 + lane;
        const float* pt = xb + n * 3;
        float x = pt[0], y = pt[1], z = pt[2];
        float dst2 = f_add(f_add(f_mul(x,x), f_mul(y,y)), f_mul(z,z));
        float dot  = f_add(f_add(f_mul(cx,x), f_mul(cy,y)), f_mul(cz,z));
        float d = f_sub(f_add(src2, dst2), f_mul(2.0f, dot));   // exact reference form
        key[j] = __longlong_as_double((long long)(((u64)__float_as_uint(d) << 32) | (u64)(unsigned)n));
    }

    double gm[8];
    #pragma unroll
    for (int g = 0; g < 8; ++g) {
        double m = key[g*8];
        #pragma unroll
        for (int e = 1; e < 8; ++e) m = fmin(m, key[g*8+e]);
        gm[g] = m;
    }

    double w = -1.0;            // below every key (tiny-negative d keys > -1)
    int myidx = 0;
    #pragma unroll 1
    for (int t = 0; t < 32; ++t) {
        double lm = fmin(fmin(fmin(gm[0], gm[1]), fmin(gm[2], gm[3])),
                         fmin(fmin(gm[4], gm[5]), fmin(gm[6], gm[7])));
        lm = fmin(lm, dpp_d<0xB1>(lm));
        lm = fmin(lm, dpp_d<0x4E>(lm));
        lm = fmin(lm, dpp_d<0x141>(lm));
        lm = fmin(lm, dpp_d<0x140>(lm));
        lm = fmin(lm, swz16_d(lm));                       // 32-lane groups
        double gmin = fmin(readlane_d(lm, 0), readlane_d(lm, 32));
        int n = (int)(unsigned)((u64)__double_as_longlong(gmin) & 0xFFFFFFFFull);
        if (lane == t) myidx = n;
        w = gmin;
        const int gs = __builtin_amdgcn_readfirstlane(n >> 9);  // group = (n>>6)>>3
        switch (gs) {
            case 0: gm[0] = rebuild8<0>(key, w); break;
            case 1: gm[1] = rebuild8<1>(key, w); break;
            case 2: gm[2] = rebuild8<2>(key, w); break;
            case 3: gm[3] = rebuild8<3>(key, w); break;
            case 4: gm[4] = rebuild8<4>(key, w); break;
            case 5: gm[5] = rebuild8<5>(key, w); break;
            case 6: gm[6] = rebuild8<6>(key, w); break;
            case 7: gm[7] = rebuild8<7>(key, w); break;
        }
    }
    if (lane < 32) out_idx[(size_t)blk * 32 + lane] = myidx;
}

// ---------------------------------------------------------------------------
// Kernel 3: 3-layer MLP + max-pool over K=32. thread = (centroid, k).
// Maxpool over the 32 k-lanes via DPP/swizzle (VALU) instead of shfl.
// ---------------------------------------------------------------------------
__global__ __launch_bounds__(256) void mlp_kernel(
    const float* __restrict__ xyz, const float* __restrict__ points,
    const int* __restrict__ knn_idx,
    const float* __restrict__ w0, const float* __restrict__ b0,
    const float* __restrict__ w1, const float* __restrict__ b1,
    const float* __restrict__ w2, const float* __restrict__ b2,
    const float* __restrict__ new_xyz, float* __restrict__ out_np)
{
    const int tid = threadIdx.x;
    const int k   = tid & 31;
    const int gs  = blockIdx.x * 8 + (tid >> 5);   // 0..8191
    const int b   = gs >> 10;
    const int n   = knn_idx[(size_t)gs * 32 + k];

    const float cx = new_xyz[gs*3+0], cy = new_xyz[gs*3+1], cz = new_xyz[gs*3+2];
    const float* pxyz = xyz + ((size_t)b * 4096 + n) * 3;
    float h0[9];
    h0[0] = pxyz[0] - cx;
    h0[1] = pxyz[1] - cy;
    h0[2] = pxyz[2] - cz;
    const float* pp = points + ((size_t)b * 4096 + n) * 6;
    #pragma unroll
    for (int c = 0; c < 6; ++c) h0[3 + c] = pp[c];

    float h1[64];
    #pragma unroll
    for (int o = 0; o < 64; ++o) {
        float acc = b0[o];
        #pragma unroll
        for (int c = 0; c < 9; ++c) acc = fmaf(h0[c], w0[o*9+c], acc);
        h1[o] = fmaxf(acc, 0.0f);
    }

    float h2[64];
    #pragma unroll
    for (int o = 0; o < 64; ++o) {
        float acc = b1[o];
        #pragma unroll
        for (int c = 0; c < 64; ++c) acc = fmaf(h1[c], w1[o*64+c], acc);
        h2[o] = fmaxf(acc, 0.0f);
    }

    float* outp = out_np + (size_t)gs * 128;
    for (int og = 0; og < 4; ++og) {
        float keep = 0.0f;
        for (int o2 = 0; o2 < 32; ++o2) {
            const int o = og * 32 + o2;
            float acc = b2[o];
            #pragma unroll
            for (int c = 0; c < 64; ++c) acc = fmaf(h2[c], w2[o*64+c], acc);
            float m = fmaxf(acc, 0.0f);
            // max over the 32 k-lanes (never crosses the 32-lane half)
            m = fmaxf(m, dpp_f<0xB1>(m));
            m = fmaxf(m, dpp_f<0x4E>(m));
            m = fmaxf(m, dpp_f<0x141>(m));
            m = fmaxf(m, dpp_f<0x140>(m));
            m = fmaxf(m, swz16_f(m));
            keep = (k == o2) ? m : keep;
        }
        outp[og * 32 + k] = keep;
    }
}

// ---------------------------------------------------------------------------
// Fallback (ws too small): fused kNN+MLP (known-correct).
// ---------------------------------------------------------------------------
__global__ __launch_bounds__(256) void knn_mlp_kernel(
    const float* __restrict__ xyz, const float* __restrict__ points,
    const float* __restrict__ w0, const float* __restrict__ b0,
    const float* __restrict__ w1, const float* __restrict__ b1,
    const float* __restrict__ w2, const float* __restrict__ b2,
    const float* __restrict__ new_xyz, float* __restrict__ out_np)
{
    const int blk    = blockIdx.x;
    const int b      = blk >> 7;
    const int s_base = (blk & 127) * 8;
    const int tid    = threadIdx.x;
    const int lane   = tid & 63;
    const int wid    = tid >> 6;

    __shared__ float sx[4096], sy[4096], sz[4096];
    __shared__ float cent[8][3];
    __shared__ int   idxbuf[8][32];

    const float* xb = xyz + (size_t)b * 4096 * 3;
    for (int n = tid; n < 4096; n += 256) {
        sx[n] = xb[n*3+0]; sy[n] = xb[n*3+1]; sz[n] = xb[n*3+2];
    }
    if (tid < 24) ((float*)cent)[tid] = new_xyz[((size_t)b * 1024 + s_base) * 3 + tid];
    __syncthreads();

    for (int si = 0; si < 2; ++si) {
        const int sl = wid * 2 + si;
        const float cx = cent[sl][0], cy = cent[sl][1], cz = cent[sl][2];
        const float src2 = f_add(f_add(f_mul(cx,cx), f_mul(cy,cy)), f_mul(cz,cz));
        float d[64];
        #pragma unroll
        for (int j = 0; j < 64; ++j) {
            int n = j * 64 + lane;
            float x = sx[n], y = sy[n], z = sz[n];
            float dst2 = f_add(f_add(f_mul(x,x), f_mul(y,y)), f_mul(z,z));
            float dot  = f_add(f_add(f_mul(cx,x), f_mul(cy,y)), f_mul(cz,z));
            d[j] = f_sub(f_add(src2, dst2), f_mul(2.0f, dot));
        }
        int myg  = 0;
        int prev = -1;
        for (int t = 0; t < 32; ++t) {
            float bv = INF_F; int bi = 0x7fffffff;
            #pragma unroll
            for (int j = 0; j < 64; ++j) {
                int n = j * 64 + lane;
                if (n == prev) d[j] = INF_F;
                float v = d[j];
                if (v < bv) { bv = v; bi = n; }
            }
            #pragma unroll
            for (int m = 1; m < 64; m <<= 1) {
                float ov = __shfl_xor(bv, m);
                int   oi = __shfl_xor(bi, m);
                if (ov < bv || (ov == bv && oi < bi)) { bv = ov; bi = oi; }
            }
            if (lane == t) myg = bi;
            prev = bi;
        }
        if (lane < 32) idxbuf[sl][lane] = myg;
    }
    __syncthreads();

    const int k   = tid & 31;
    const int sl2 = tid >> 5;
    const int s   = s_base + sl2;
    const int n   = idxbuf[sl2][k];

    const float cx = cent[sl2][0], cy = cent[sl2][1], cz = cent[sl2][2];
    float h0[9];
    h0[0] = sx[n] - cx;
    h0[1] = sy[n] - cy;
    h0[2] = sz[n] - cz;
    const float* pp = points + ((size_t)b * 4096 + n) * 6;
    #pragma unroll
    for (int c = 0; c < 6; ++c) h0[3 + c] = pp[c];

    float h1[64];
    #pragma unroll
    for (int o = 0; o < 64; ++o) {
        float acc = b0[o];
        #pragma unroll
        for (int c = 0; c < 9; ++c) acc = fmaf(h0[c], w0[o*9+c], acc);
        h1[o] = fmaxf(acc, 0.0f);
    }
    float h2[64];
    #pragma unroll
    for (int o = 0; o < 64; ++o) {
        float acc = b1[o];
        #pragma unroll
        for (int c = 0; c < 64; ++c) acc = fmaf(h1[c], w1[o*64+c], acc);
        h2[o] = fmaxf(acc, 0.0f);
    }
    float* outp = out_np + ((size_t)b * 1024 + s) * 128;
    for (int og = 0; og < 4; ++og) {
        float keep = 0.0f;
        for (int o2 = 0; o2 < 32; ++o2) {
            const int o = og * 32 + o2;
            float acc = b2[o];
            #pragma unroll
            for (int c = 0; c < 64; ++c) acc = fmaf(h2[c], w2[o*64+c], acc);
            float m = fmaxf(acc, 0.0f);
            #pragma unroll
            for (int mm = 1; mm < 32; mm <<= 1)
                m = fmaxf(m, __shfl_xor(m, mm));
            keep = (k == o2) ? m : keep;
        }
        outp[og * 32 + k] = keep;
    }
}

extern "C" void kernel_launch(void* const* d_in, const int* in_sizes, int n_in,
                              void* d_out, int out_size, void* d_ws, size_t ws_size,
                              hipStream_t stream) {
    const float* xyz           = (const float*)d_in[0];
    const float* points        = (const float*)d_in[1];
    const int*   farthest_init = (const int*)  d_in[2];
    const float* w0 = (const float*)d_in[3];
    const float* b0 = (const float*)d_in[4];
    const float* w1 = (const float*)d_in[5];
    const float* b1 = (const float*)d_in[6];
    const float* w2 = (const float*)d_in[7];
    const float* b2 = (const float*)d_in[8];

    float* out        = (float*)d_out;
    float* new_xyz    = out;                 // [8,1024,3]
    float* new_points = out + 8 * 1024 * 3;  // [8,1024,128]

    fps_kernel<<<8, 256, 0, stream>>>(xyz, farthest_init, new_xyz);

    if (ws_size >= (size_t)(8192 * 32 * sizeof(int))) {
        int* knn_idx = (int*)d_ws;
        knn_kernel<<<2048, 256, 0, stream>>>(xyz, new_xyz, knn_idx);
        mlp_kernel<<<1024, 256, 0, stream>>>(xyz, points, knn_idx,
                                             w0, b0, w1, b1, w2, b2,
                                             new_xyz, new_points);
    } else {
        knn_mlp_kernel<<<1024, 256, 0, stream>>>(xyz, points, w0, b0, w1, b1, w2, b2,
                                                 new_xyz, new_points);
    }
}

// Round 5
// 772.432 us; speedup vs baseline: 2.7667x; 1.0299x over previous
//
#include <hip/hip_runtime.h>

#define INF_F 3.402823466e+38f
typedef unsigned long long u64;
typedef __attribute__((ext_vector_type(2))) float f32x2;

__device__ __forceinline__ float f_add(float a, float b){ return __fadd_rn(a,b); }
__device__ __forceinline__ float f_sub(float a, float b){ return __fsub_rn(a,b); }
__device__ __forceinline__ float f_mul(float a, float b){ return __fmul_rn(a,b); }

// Packed fp32 (VOP3P) — same RN rounding as scalar, 2 elems/instr.
__device__ __forceinline__ f32x2 pk_add(f32x2 a, f32x2 b){ f32x2 d; asm("v_pk_add_f32 %0, %1, %2" : "=v"(d) : "v"(a), "v"(b)); return d; }
__device__ __forceinline__ f32x2 pk_mul(f32x2 a, f32x2 b){ f32x2 d; asm("v_pk_mul_f32 %0, %1, %2" : "=v"(d) : "v"(a), "v"(b)); return d; }

// DPP cross-lane (pure VALU). 0xB1=xor1, 0x4E=xor2, 0x141=xor4(eq), 0x140=xor8(eq)
template<int CTRL>
__device__ __forceinline__ double dpp_d(double x) {
    u64 u = (u64)__double_as_longlong(x);
    int lo = __builtin_amdgcn_update_dpp(0, (int)(unsigned)u,        CTRL, 0xF, 0xF, true);
    int hi = __builtin_amdgcn_update_dpp(0, (int)(unsigned)(u>>32), CTRL, 0xF, 0xF, true);
    return __longlong_as_double((long long)(((u64)(unsigned)hi << 32) | (unsigned)lo));
}
template<int CTRL>
__device__ __forceinline__ float dpp_f(float x) {
    int r = __builtin_amdgcn_update_dpp(0, __float_as_int(x), CTRL, 0xF, 0xF, true);
    return __int_as_float(r);
}
__device__ __forceinline__ double swz16_d(double x) {   // xor-16 partner
    u64 u = (u64)__double_as_longlong(x);
    int lo = __builtin_amdgcn_ds_swizzle((int)(unsigned)u,        0x401F);
    int hi = __builtin_amdgcn_ds_swizzle((int)(unsigned)(u>>32), 0x401F);
    return __longlong_as_double((long long)(((u64)(unsigned)hi << 32) | (unsigned)lo));
}
__device__ __forceinline__ float swz16_f(float x) {
    return __int_as_float(__builtin_amdgcn_ds_swizzle(__float_as_int(x), 0x401F));
}
__device__ __forceinline__ double readlane_d(double x, int l) {
    u64 u = (u64)__double_as_longlong(x);
    int lo = __builtin_amdgcn_readlane((int)(unsigned)u,        l);
    int hi = __builtin_amdgcn_readlane((int)(unsigned)(u>>32), l);
    return __longlong_as_double((long long)(((u64)(unsigned)hi << 32) | (unsigned)lo));
}
__device__ __forceinline__ double pack_key(float nd, unsigned low) {
    return __longlong_as_double((long long)(((u64)__float_as_uint(nd) << 32) | (u64)low));
}

// ---------------------------------------------------------------------------
// Kernel 1: FPS. One 256-thread block per batch. Register-lean: persistent
// state = px/py/pz (48 VGPR) + dist (16); keys folded on the fly into 4
// running-max chains; full in-wave reduce (DPP+swz16+readlane, no LDS);
// 1 f64 LDS slot per wave. launch_bounds(256,1) -> no heuristic VGPR cap.
// Argmax key = (bits(nd)<<32)|(4095-n) -> fmax == (val, lowest-idx) == np.
// ---------------------------------------------------------------------------
__global__ __launch_bounds__(256, 1) void fps_kernel(
    const float* __restrict__ xyz, const int* __restrict__ farthest_init,
    float* __restrict__ out_new_xyz)
{
    const int b    = blockIdx.x;
    const int tid  = threadIdx.x;
    const int lane = tid & 63;
    const int wid  = tid >> 6;

    __shared__ float  sx[4096], sy[4096], sz[4096];
    __shared__ int    hist[1024];
    __shared__ double red[2][4];

    const float* xb = xyz + (size_t)b * 4096 * 3;
    for (int n = tid; n < 4096; n += 256) {
        sx[n] = xb[n*3+0]; sy[n] = xb[n*3+1]; sz[n] = xb[n*3+2];
    }
    __syncthreads();

    f32x2 px[8], py[8], pz[8], dist2[8];
    #pragma unroll
    for (int jp = 0; jp < 8; ++jp) {
        const int n0 = (2*jp) * 256 + tid, n1 = n0 + 256;
        px[jp] = (f32x2){sx[n0], sx[n1]};
        py[jp] = (f32x2){sy[n0], sy[n1]};
        pz[jp] = (f32x2){sz[n0], sz[n1]};
        dist2[jp] = (f32x2){1e10f, 1e10f};
    }
    const unsigned lowbase = 4095u - (unsigned)tid;

    int far = farthest_init[b];
    int p = 0;
    #pragma unroll 1
    for (int it = 0; it < 1024; ++it) {
        if (tid == 0) hist[it] = far;
        const float cx = sx[far], cy = sy[far], cz = sz[far];
        const f32x2 ncx = (f32x2){-cx, -cx};
        const f32x2 ncy = (f32x2){-cy, -cy};
        const f32x2 ncz = (f32x2){-cz, -cz};

        double a0 = -1.0, a1 = -1.0, a2 = -1.0, a3 = -1.0;  // 4 indep chains
        #pragma unroll
        for (int jp = 0; jp < 8; ++jp) {
            f32x2 dx = pk_add(px[jp], ncx);          // x + (-c) == x - c exactly
            f32x2 dy = pk_add(py[jp], ncy);
            f32x2 dz = pk_add(pz[jp], ncz);
            // exact reference order: (dx^2 + dy^2) + dz^2, no FMA
            f32x2 d2 = pk_add(pk_add(pk_mul(dx,dx), pk_mul(dy,dy)), pk_mul(dz,dz));
            float nd0 = fminf(dist2[jp][0], d2[0]); dist2[jp][0] = nd0;
            float nd1 = fminf(dist2[jp][1], d2[1]); dist2[jp][1] = nd1;
            double k0 = pack_key(nd0, lowbase - (unsigned)((2*jp)*256));
            double k1 = pack_key(nd1, lowbase - (unsigned)((2*jp+1)*256));
            if (jp & 1) { a2 = fmax(a2, k0); a3 = fmax(a3, k1); }
            else        { a0 = fmax(a0, k0); a1 = fmax(a1, k1); }
        }
        double best = fmax(fmax(a0, a1), fmax(a2, a3));
        best = fmax(best, dpp_d<0xB1>(best));
        best = fmax(best, dpp_d<0x4E>(best));
        best = fmax(best, dpp_d<0x141>(best));
        best = fmax(best, dpp_d<0x140>(best));
        best = fmax(best, swz16_d(best));            // -> 32-lane groups
        double wb = fmax(readlane_d(best, 0), readlane_d(best, 32));  // wave max
        if (lane == 0) red[p][wid] = wb;
        __syncthreads();
        double g = fmax(fmax(red[p][0], red[p][1]), fmax(red[p][2], red[p][3]));
        far = 4095 - (int)(unsigned)((u64)__double_as_longlong(g) & 0xFFFFFFFFull);
        p ^= 1;   // double-buffered slots: 1 barrier per iteration
    }
    __syncthreads();
    #pragma unroll
    for (int q = 0; q < 4; ++q) {
        int s  = q * 256 + tid;
        int id = hist[s];
        float* o = out_new_xyz + ((size_t)b * 1024 + s) * 3;
        o[0] = sx[id]; o[1] = sy[id]; o[2] = sz[id];
    }
}

// ---------------------------------------------------------------------------
// Kernel 2: kNN top-32. One wave per centroid (4 waves/block, no barriers).
// f64 keys (bits(d)<<32)|n, distinct -> min == (dist, lowest idx) == top_k.
// Per lane: 8 cached group-minima; per round rebuild only the winner's group.
// launch_bounds(256,1): key[64]=128 VGPRs must stay in registers.
// ---------------------------------------------------------------------------
template<int G>
__device__ __forceinline__ double rebuild8(const double (&key)[64], double w) {
    const double DINF = __builtin_huge_val();
    double m = DINF;
    #pragma unroll
    for (int e = 0; e < 8; ++e) {
        double v = key[G*8+e];
        v = (v > w) ? v : DINF;
        m = fmin(m, v);
    }
    return m;
}

__global__ __launch_bounds__(256, 1) void knn_kernel(
    const float* __restrict__ xyz, const float* __restrict__ new_xyz,
    int* __restrict__ out_idx)
{
    const int tid  = threadIdx.x;
    const int lane = tid & 63;
    const int wid  = tid >> 6;
    const int blk  = blockIdx.x * 4 + wid;   // 0..8191 = b*1024 + s
    const int b    = blk >> 10;
    const double DINF = __builtin_huge_val();

    const float* xb = xyz + (size_t)b * 4096 * 3;
    const float* cp = new_xyz + (size_t)blk * 3;
    const float cx = cp[0], cy = cp[1], cz = cp[2];
    const float src2 = f_add(f_add(f_mul(cx,cx), f_mul(cy,cy)), f_mul(cz,cz));

    double key[64];
    #pragma unroll
    for (int j = 0; j < 64; ++j) {
        const int n = j * 64 + lane;
        const float* pt = xb + n * 3;
        float x = pt[0], y = pt[1], z = pt[2];
        float dst2 = f_add(f_add(f_mul(x,x), f_mul(y,y)), f_mul(z,z));
        float dot  = f_add(f_add(f_mul(cx,x), f_mul(cy,y)), f_mul(cz,z));
        float d = f_sub(f_add(src2, dst2), f_mul(2.0f, dot));   // exact reference form
        key[j] = __longlong_as_double((long long)(((u64)__float_as_uint(d) << 32) | (u64)(unsigned)n));
    }

    double gm[8];
    #pragma unroll
    for (int g = 0; g < 8; ++g) {
        double m = key[g*8];
        #pragma unroll
        for (int e = 1; e < 8; ++e) m = fmin(m, key[g*8+e]);
        gm[g] = m;
    }

    double w = -1.0;            // below every key (tiny-negative d keys > -1)
    int myidx = 0;
    #pragma unroll 1
    for (int t = 0; t < 32; ++t) {
        double lm = fmin(fmin(fmin(gm[0], gm[1]), fmin(gm[2], gm[3])),
                         fmin(fmin(gm[4], gm[5]), fmin(gm[6], gm[7])));
        lm = fmin(lm, dpp_d<0xB1>(lm));
        lm = fmin(lm, dpp_d<0x4E>(lm));
        lm = fmin(lm, dpp_d<0x141>(lm));
        lm = fmin(lm, dpp_d<0x140>(lm));
        lm = fmin(lm, swz16_d(lm));                       // 32-lane groups
        double gmin = fmin(readlane_d(lm, 0), readlane_d(lm, 32));
        int n = (int)(unsigned)((u64)__double_as_longlong(gmin) & 0xFFFFFFFFull);
        if (lane == t) myidx = n;
        w = gmin;
        const int gs = __builtin_amdgcn_readfirstlane(n >> 9);  // group = (n>>6)>>3
        switch (gs) {
            case 0: gm[0] = rebuild8<0>(key, w); break;
            case 1: gm[1] = rebuild8<1>(key, w); break;
            case 2: gm[2] = rebuild8<2>(key, w); break;
            case 3: gm[3] = rebuild8<3>(key, w); break;
            case 4: gm[4] = rebuild8<4>(key, w); break;
            case 5: gm[5] = rebuild8<5>(key, w); break;
            case 6: gm[6] = rebuild8<6>(key, w); break;
            case 7: gm[7] = rebuild8<7>(key, w); break;
        }
    }
    if (lane < 32) out_idx[(size_t)blk * 32 + lane] = myidx;
}

// ---------------------------------------------------------------------------
// Kernel 3: 3-layer MLP + max-pool over K=32. thread = (centroid, k).
// Maxpool over the 32 k-lanes via DPP/swizzle (VALU). launch_bounds(256,1):
// h1+h2 = 128 VGPRs must stay in registers.
// ---------------------------------------------------------------------------
__global__ __launch_bounds__(256, 1) void mlp_kernel(
    const float* __restrict__ xyz, const float* __restrict__ points,
    const int* __restrict__ knn_idx,
    const float* __restrict__ w0, const float* __restrict__ b0,
    const float* __restrict__ w1, const float* __restrict__ b1,
    const float* __restrict__ w2, const float* __restrict__ b2,
    const float* __restrict__ new_xyz, float* __restrict__ out_np)
{
    const int tid = threadIdx.x;
    const int k   = tid & 31;
    const int gs  = blockIdx.x * 8 + (tid >> 5);   // 0..8191
    const int b   = gs >> 10;
    const int n   = knn_idx[(size_t)gs * 32 + k];

    const float cx = new_xyz[gs*3+0], cy = new_xyz[gs*3+1], cz = new_xyz[gs*3+2];
    const float* pxyz = xyz + ((size_t)b * 4096 + n) * 3;
    float h0[9];
    h0[0] = pxyz[0] - cx;
    h0[1] = pxyz[1] - cy;
    h0[2] = pxyz[2] - cz;
    const float* pp = points + ((size_t)b * 4096 + n) * 6;
    #pragma unroll
    for (int c = 0; c < 6; ++c) h0[3 + c] = pp[c];

    float h1[64];
    #pragma unroll
    for (int o = 0; o < 64; ++o) {
        float acc = b0[o];
        #pragma unroll
        for (int c = 0; c < 9; ++c) acc = fmaf(h0[c], w0[o*9+c], acc);
        h1[o] = fmaxf(acc, 0.0f);
    }

    float h2[64];
    #pragma unroll
    for (int o = 0; o < 64; ++o) {
        float acc = b1[o];
        #pragma unroll
        for (int c = 0; c < 64; ++c) acc = fmaf(h1[c], w1[o*64+c], acc);
        h2[o] = fmaxf(acc, 0.0f);
    }

    float* outp = out_np + (size_t)gs * 128;
    for (int og = 0; og < 4; ++og) {
        float keep = 0.0f;
        for (int o2 = 0; o2 < 32; ++o2) {
            const int o = og * 32 + o2;
            float acc = b2[o];
            #pragma unroll
            for (int c = 0; c < 64; ++c) acc = fmaf(h2[c], w2[o*64+c], acc);
            float m = fmaxf(acc, 0.0f);
            // max over the 32 k-lanes (never crosses the 32-lane half)
            m = fmaxf(m, dpp_f<0xB1>(m));
            m = fmaxf(m, dpp_f<0x4E>(m));
            m = fmaxf(m, dpp_f<0x141>(m));
            m = fmaxf(m, dpp_f<0x140>(m));
            m = fmaxf(m, swz16_f(m));
            keep = (k == o2) ? m : keep;
        }
        outp[og * 32 + k] = keep;
    }
}

// ---------------------------------------------------------------------------
// Fallback (ws too small): fused kNN+MLP (known-correct).
// ---------------------------------------------------------------------------
__global__ __launch_bounds__(256) void knn_mlp_kernel(
    const float* __restrict__ xyz, const float* __restrict__ points,
    const float* __restrict__ w0, const float* __restrict__ b0,
    const float* __restrict__ w1, const float* __restrict__ b1,
    const float* __restrict__ w2, const float* __restrict__ b2,
    const float* __restrict__ new_xyz, float* __restrict__ out_np)
{
    const int blk    = blockIdx.x;
    const int b      = blk >> 7;
    const int s_base = (blk & 127) * 8;
    const int tid    = threadIdx.x;
    const int lane   = tid & 63;
    const int wid    = tid >> 6;

    __shared__ float sx[4096], sy[4096], sz[4096];
    __shared__ float cent[8][3];
    __shared__ int   idxbuf[8][32];

    const float* xb = xyz + (size_t)b * 4096 * 3;
    for (int n = tid; n < 4096; n += 256) {
        sx[n] = xb[n*3+0]; sy[n] = xb[n*3+1]; sz[n] = xb[n*3+2];
    }
    if (tid < 24) ((float*)cent)[tid] = new_xyz[((size_t)b * 1024 + s_base) * 3 + tid];
    __syncthreads();

    for (int si = 0; si < 2; ++si) {
        const int sl = wid * 2 + si;
        const float cx = cent[sl][0], cy = cent[sl][1], cz = cent[sl][2];
        const float src2 = f_add(f_add(f_mul(cx,cx), f_mul(cy,cy)), f_mul(cz,cz));
        float d[64];
        #pragma unroll
        for (int j = 0; j < 64; ++j) {
            int n = j * 64 + lane;
            float x = sx[n], y = sy[n], z = sz[n];
            float dst2 = f_add(f_add(f_mul(x,x), f_mul(y,y)), f_mul(z,z));
            float dot  = f_add(f_add(f_mul(cx,x), f_mul(cy,y)), f_mul(cz,z));
            d[j] = f_sub(f_add(src2, dst2), f_mul(2.0f, dot));
        }
        int myg  = 0;
        int prev = -1;
        for (int t = 0; t < 32; ++t) {
            float bv = INF_F; int bi = 0x7fffffff;
            #pragma unroll
            for (int j = 0; j < 64; ++j) {
                int n = j * 64 + lane;
                if (n == prev) d[j] = INF_F;
                float v = d[j];
                if (v < bv) { bv = v; bi = n; }
            }
            #pragma unroll
            for (int m = 1; m < 64; m <<= 1) {
                float ov = __shfl_xor(bv, m);
                int   oi = __shfl_xor(bi, m);
                if (ov < bv || (ov == bv && oi < bi)) { bv = ov; bi = oi; }
            }
            if (lane == t) myg = bi;
            prev = bi;
        }
        if (lane < 32) idxbuf[sl][lane] = myg;
    }
    __syncthreads();

    const int k   = tid & 31;
    const int sl2 = tid >> 5;
    const int s   = s_base + sl2;
    const int n   = idxbuf[sl2][k];

    const float cx = cent[sl2][0], cy = cent[sl2][1], cz = cent[sl2][2];
    float h0[9];
    h0[0] = sx[n] - cx;
    h0[1] = sy[n] - cy;
    h0[2] = sz[n] - cz;
    const float* pp = points + ((size_t)b * 4096 + n) * 6;
    #pragma unroll
    for (int c = 0; c < 6; ++c) h0[3 + c] = pp[c];

    float h1[64];
    #pragma unroll
    for (int o = 0; o < 64; ++o) {
        float acc = b0[o];
        #pragma unroll
        for (int c = 0; c < 9; ++c) acc = fmaf(h0[c], w0[o*9+c], acc);
        h1[o] = fmaxf(acc, 0.0f);
    }
    float h2[64];
    #pragma unroll
    for (int o = 0; o < 64; ++o) {
        float acc = b1[o];
        #pragma unroll
        for (int c = 0; c < 64; ++c) acc = fmaf(h1[c], w1[o*64+c], acc);
        h2[o] = fmaxf(acc, 0.0f);
    }
    float* outp = out_np + ((size_t)b * 1024 + s) * 128;
    for (int og = 0; og < 4; ++og) {
        float keep = 0.0f;
        for (int o2 = 0; o2 < 32; ++o2) {
            const int o = og * 32 + o2;
            float acc = b2[o];
            #pragma unroll
            for (int c = 0; c < 64; ++c) acc = fmaf(h2[c], w2[o*64+c], acc);
            float m = fmaxf(acc, 0.0f);
            #pragma unroll
            for (int mm = 1; mm < 32; mm <<= 1)
                m = fmaxf(m, __shfl_xor(m, mm));
            keep = (k == o2) ? m : keep;
        }
        outp[og * 32 + k] = keep;
    }
}

extern "C" void kernel_launch(void* const* d_in, const int* in_sizes, int n_in,
                              void* d_out, int out_size, void* d_ws, size_t ws_size,
                              hipStream_t stream) {
    const float* xyz           = (const float*)d_in[0];
    const float* points        = (const float*)d_in[1];
    const int*   farthest_init = (const int*)  d_in[2];
    const float* w0 = (const float*)d_in[3];
    const float* b0 = (const float*)d_in[4];
    const float* w1 = (const float*)d_in[5];
    const float* b1 = (const float*)d_in[6];
    const float* w2 = (const float*)d_in[7];
    const float* b2 = (const float*)d_in[8];

    float* out        = (float*)d_out;
    float* new_xyz    = out;                 // [8,1024,3]
    float* new_points = out + 8 * 1024 * 3;  // [8,1024,128]

    fps_kernel<<<8, 256, 0, stream>>>(xyz, farthest_init, new_xyz);

    if (ws_size >= (size_t)(8192 * 32 * sizeof(int))) {
        int* knn_idx = (int*)d_ws;
        knn_kernel<<<2048, 256, 0, stream>>>(xyz, new_xyz, knn_idx);
        mlp_kernel<<<1024, 256, 0, stream>>>(xyz, points, knn_idx,
                                             w0, b0, w1, b1, w2, b2,
                                             new_xyz, new_points);
    } else {
        knn_mlp_kernel<<<1024, 256, 0, stream>>>(xyz, points, w0, b0, w1, b1, w2, b2,
                                                 new_xyz, new_points);
    }
}